// Round 11
// baseline (349.110 us; speedup 1.0000x reference)
//
#include <hip/hip_runtime.h>
#include <hip/hip_bf16.h>
#include <hip/hip_cooperative_groups.h>

namespace cg = cooperative_groups;

typedef __hip_bfloat16 bf16;
typedef __bf16 bf16x8 __attribute__((ext_vector_type(8)));
typedef float f32x4 __attribute__((ext_vector_type(4)));

#define NEG_SLOPE 0.2f
#define F32_THRESH 256

// ---------------- helpers ----------------------------------------------------

__device__ __forceinline__ bool is_f32(const int* fcnt) { return *fcnt > F32_THRESH; }

__device__ __forceinline__ float ld_f(const void* p, long long i, bool f32) {
    return f32 ? ((const float*)p)[i] : __bfloat162float(((const bf16*)p)[i]);
}

__device__ __forceinline__ float b2f(unsigned hs) {
    return __uint_as_float(hs << 16);
}

__device__ __forceinline__ unsigned pack_bf2(float a, float b) {
    union { bf16 h[2]; unsigned u; } p;
    p.h[0] = __float2bfloat16(a);
    p.h[1] = __float2bfloat16(b);
    return p.u;
}

__device__ __forceinline__ void load_lds16(const void* g, void* l) {
    __builtin_amdgcn_global_load_lds(
        (const __attribute__((address_space(1))) void*)g,
        (__attribute__((address_space(3))) void*)l, 16, 0, 0);
}

template <int CPL> struct FV;
template <> struct FV<8> {
    uint4 v;
    __device__ __forceinline__ void load(const bf16* p) { v = *(const uint4*)p; }
    __device__ __forceinline__ void fma(float* acc, float w) const {
        unsigned uu[4] = {v.x, v.y, v.z, v.w};
#pragma unroll
        for (int q = 0; q < 4; q++) {
            acc[2 * q] += w * b2f(uu[q] & 0xFFFFu);
            acc[2 * q + 1] += w * b2f(uu[q] >> 16);
        }
    }
};
template <> struct FV<2> {
    unsigned v;
    __device__ __forceinline__ void load(const bf16* p) { v = *(const unsigned*)p; }
    __device__ __forceinline__ void fma(float* acc, float w) const {
        acc[0] += w * b2f(v & 0xFFFFu);
        acc[1] += w * b2f(v >> 16);
    }
};

__device__ __forceinline__ int edge_val(const void* idx, long long i, int is64) {
    return is64 ? (int)((const long long*)idx)[i] : ((const int*)idx)[i];
}

// ---------------- device phase bodies (shared by coop + fallback) -----------

template <int BN, bool SEL, int H>
__device__ void dev_gemm(char* smem, int bx, int by,
                         const void* Araw, const bf16* Aconv, const bf16* Atail,
                         const int* fcnt, const bf16* __restrict__ Bt,
                         bf16* __restrict__ C, const void* a_s, const void* a_d,
                         float* __restrict__ als, float* __restrict__ ald,
                         int M, int Nn, int K, int nfull) {
    constexpr int BM = 128, BK = 32;
    constexpr int NT = BN / 32;
    const int m0 = bx * BM;
    const int n0 = by * BN;
    __bf16* As = (__bf16*)smem;               // [128][32]
    __bf16* Bs = (__bf16*)(smem + 8192);      // [BN][32]
    const int tid = threadIdx.x;
    const int wave = tid >> 6;
    const int lane = tid & 63;
    const int wm = (wave & 1) * 64;
    const int wn = (wave >> 1) * (NT * 16);
    const int lm = lane & 15;
    const int quad = lane >> 4;
    const int srow = tid >> 2;
    const int scol = (tid & 3) * 8;

    f32x4 acc[4][NT];
#pragma unroll
    for (int mt = 0; mt < 4; mt++)
#pragma unroll
        for (int nt = 0; nt < NT; nt++) acc[mt][nt] = (f32x4){0.f, 0.f, 0.f, 0.f};

    const bf16* Abase;
    int arow0;
    if (SEL) {
        const bf16* Asel = is_f32(fcnt) ? Aconv : (const bf16*)Araw;
        if (bx < nfull) { Abase = Asel; arow0 = m0; }
        else { Abase = Atail; arow0 = 0; }
    } else {
        Abase = (const bf16*)Araw;
        arow0 = m0;
    }

    const char* Ab = (const char*)(Abase + (size_t)(arow0 + srow) * K + scol);
    const char* Bb = (const char*)(Bt + (size_t)(n0 + srow) * K + scol);
    char* ldsA = (char*)As + wave * 1024;
    char* ldsB = (char*)Bs + wave * 1024;
    const size_t rstep = (size_t)64 * K * 2;

    for (int k0 = 0; k0 < K; k0 += BK) {
        __syncthreads();
        const size_t kb = (size_t)k0 * 2;
        load_lds16(Ab + kb, ldsA);
        load_lds16(Ab + kb + rstep, ldsA + 4096);
        load_lds16(Bb + kb, ldsB);
        if (BN == 128) load_lds16(Bb + kb + rstep, ldsB + 4096);
        __syncthreads();
        bf16x8 af[4], bfv[NT];
#pragma unroll
        for (int mt = 0; mt < 4; mt++)
            af[mt] = *(const bf16x8*)(As + (wm + mt * 16 + lm) * 32 + quad * 8);
#pragma unroll
        for (int nt = 0; nt < NT; nt++)
            bfv[nt] = *(const bf16x8*)(Bs + (wn + nt * 16 + lm) * 32 + quad * 8);
#pragma unroll
        for (int mt = 0; mt < 4; mt++)
#pragma unroll
            for (int nt = 0; nt < NT; nt++)
                acc[mt][nt] = __builtin_amdgcn_mfma_f32_16x16x32_bf16(
                    af[mt], bfv[nt], acc[mt][nt], 0, 0, 0);
    }

#pragma unroll
    for (int mt = 0; mt < 4; mt++) {
        int rb = m0 + wm + mt * 16 + quad * 4;
#pragma unroll
        for (int nt = 0; nt < NT; nt++) {
            int col = n0 + wn + nt * 16 + lm;
#pragma unroll
            for (int r = 0; r < 4; r++) {
                int row = rb + r;
                if (row < M) C[(size_t)row * Nn + col] = __float2bfloat16(acc[mt][nt][r]);
            }
        }
    }

    // fused attention-logit partials: al[row,head] += sum_col acc*a[col]
    const bool f32 = is_f32(fcnt);
    float sa_[NT], sd_[NT];
#pragma unroll
    for (int nt = 0; nt < NT; nt++) {
        int col = n0 + wn + nt * 16 + lm;
        sa_[nt] = ld_f(a_s, col, f32);
        sd_[nt] = ld_f(a_d, col, f32);
    }
    const int head = (H == 4) ? (n0 >> 7) : 0;
#pragma unroll
    for (int mt = 0; mt < 4; mt++) {
#pragma unroll
        for (int r = 0; r < 4; r++) {
            float ps_ = 0.f, pd_ = 0.f;
#pragma unroll
            for (int nt = 0; nt < NT; nt++) {
                float v = acc[mt][nt][r];
                ps_ += v * sa_[nt];
                pd_ += v * sd_[nt];
            }
#pragma unroll
            for (int off = 1; off < 16; off <<= 1) {
                ps_ += __shfl_xor(ps_, off, 64);
                pd_ += __shfl_xor(pd_, off, 64);
            }
            int row = m0 + wm + mt * 16 + quad * 4 + r;
            if (lm == 0 && row < M) {
                atomicAdd(&als[(size_t)row * H + head], ps_);
                atomicAdd(&ald[(size_t)row * H + head], pd_);
            }
        }
    }
}

template <int C, int H, bool ELU, bool DYN_OUT>
__device__ void dev_agg(char* smem, int n, const bf16* __restrict__ feat,
                        const float* __restrict__ als, const float* __restrict__ ald,
                        const int* __restrict__ rowptr, const int* __restrict__ csr_src,
                        const void* bias, const int* fcnt, void* outp, int N, int E) {
    constexpr int CPL = C / 64;
    constexpr int Ch = C / H;
    constexpr int WST = (H == 4) ? 5 : 1;
    float* red = (float*)smem;            // [4][C]
    float* s_w = red + 4 * C;             // [64*WST]
    int* s_src = (int*)(s_w + 64 * WST);  // [64]
    float* ps = (float*)(s_src + 64);     // [4][H]
    const int tid = threadIdx.x;
    const int wave = tid >> 6;
    const int lane = tid & 63;
    const int c0 = lane * CPL;
    const int head = c0 / Ch;

    int start = rowptr[n];
    if (start < 0) start = 0;
    int end = rowptr[n + 1];
    if (end > E) end = E;
    int deg = end - start;
    if (deg < 0) deg = 0;

    float acc[CPL] = {};
    float psum = 0.f;

    for (int base = 0; base < deg; base += 64) {
        int cnt = min(64, deg - base);
        __syncthreads();
        if (H == 4) {
            int e_ = tid & 63, h_ = tid >> 6;
            if (e_ < cnt) {
                int s = csr_src[start + base + e_];
                if ((unsigned)s >= (unsigned)N) s = 0;
                if (h_ == 0) s_src[e_] = s;
                float l = als[(size_t)s * 4 + h_] + ald[(size_t)n * 4 + h_];
                l = l > 0.f ? l : NEG_SLOPE * l;
                s_w[e_ * 5 + h_] = __expf(fminf(l, 60.f));
            }
        } else {
            if (tid < cnt) {
                int s = csr_src[start + base + tid];
                if ((unsigned)s >= (unsigned)N) s = 0;
                s_src[tid] = s;
                float l = als[s] + ald[n];
                l = l > 0.f ? l : NEG_SLOPE * l;
                s_w[tid] = __expf(fminf(l, 60.f));
            }
        }
        __syncthreads();
#pragma unroll 4
        for (int e = wave; e < cnt; e += 4) {
            int s = s_src[e];
            float wl = (H == 4) ? s_w[e * 5 + head] : s_w[e];
            psum += wl;
            FV<CPL> f;
            f.load(feat + (size_t)s * C + c0);
            f.fma(acc, wl);
        }
    }

    __syncthreads();  // protect red/ps vs previous node's epilogue readers
#pragma unroll
    for (int j = 0; j < CPL; j++) red[wave * C + c0 + j] = acc[j];
    if ((lane & 15) == 0) ps[wave * H + head] = psum;
    __syncthreads();

    const bool f32 = is_f32(fcnt);
    for (int c = tid; c < C; c += 256) {
        int h = c / Ch;
        float sv = 0.f;
        float dn = 1e-16f;
#pragma unroll
        for (int w2 = 0; w2 < 4; w2++) {
            sv += red[w2 * C + c];
            dn += ps[w2 * H + h];
        }
        float v = sv / dn + ld_f(bias, c, f32);
        if (ELU) v = v > 0.f ? v : expf(v) - 1.f;
        size_t oi = (size_t)n * C + c;
        if (DYN_OUT && f32) ((float*)outp)[oi] = v;
        else ((bf16*)outp)[oi] = __float2bfloat16(v);
    }
}

// ---------------- mega kernel (single cooperative launch) -------------------

struct MegaArgs {
    const void* x_raw; const void* eidx;
    const void* W1; const void* as1; const void* ad1; const void* b1;
    const void* W2; const void* as2; const void* ad2; const void* b2;
    bf16* xb; bf16* xtail; bf16* h1; bf16* hagg; bf16* W1t; bf16* W2t;
    int* rowptr; int* csr_src; int* zbase; int* bsum;
    void* out;
    int N, K, C1, C2, E0, E, Mpad, nfull;
    long long nw_cap; int nh_cap;
};

__global__ __launch_bounds__(256) void k_mega(MegaArgs a) {
    cg::grid_group grid = cg::this_grid();
    __shared__ __align__(16) char smem[16640];

    const int blk = blockIdx.x;
    const int tid = threadIdx.x;
    const int G = gridDim.x;
    const long long gt = (long long)blk * 256 + tid;
    const long long GT = (long long)G * 256;

    const int N = a.N, K = a.K, C1 = a.C1, C2 = a.C2;
    const int E0 = a.E0, E = a.E, Mpad = a.Mpad, nfull = a.nfull;
    int* deg = a.zbase;
    int* cursor = a.zbase + N;
    float* al1s = (float*)(a.zbase + 2 * N);
    float* al1d = al1s + 4 * N;
    float* al2s = al1d + 4 * N;
    float* al2d = al2s + N;
    int* iflag = a.zbase + 12 * N;
    int* fcnt = a.zbase + 12 * N + 1;
    bf16* h2 = a.xb;  // alias: xb dead after gemm1

    // ---- P0: zero control region + hagg pad rows ----
    {
        long long zn = 12LL * N + 2;
        for (long long i = gt; i < zn; i += GT) a.zbase[i] = 0;
        unsigned* hp = (unsigned*)(a.hagg + (size_t)N * C1);
        long long pw = (long long)(Mpad - N) * C1 / 2;
        for (long long i = gt; i < pw; i += GT) hp[i] = 0;
    }
    grid.sync();

    // ---- P1: probe (dtype sniff + int width) ----
    {
        const unsigned* xw = (const unsigned*)a.x_raw;
        int c = 0;
        for (long long i = gt; i < a.nw_cap; i += GT)
            if ((xw[i] & 0x7F80u) == 0x7F80u) c++;
        if (c) atomicAdd(fcnt, c);
        const int* idx = (const int*)a.eidx;
        int any = 0;
        for (long long i = gt; i < a.nh_cap; i += GT)
            if (idx[2 * i + 1] != 0) any = 1;
        if (any) atomicOr(iflag, 1);
    }
    grid.sync();

    // ---- P2: count + prep (W transposes, x convert/tail) ----
    {
        const int is64 = (*iflag == 0);
        const bool f32 = is_f32(fcnt);
        for (long long e = gt; e < E; e += GT) {
            int d = (e < E0) ? edge_val(a.eidx, (long long)E0 + e, is64) : (int)(e - E0);
            if ((unsigned)d >= (unsigned)N) d = 0;
            atomicAdd(&deg[d], 1);
        }
        for (long long i = gt; i < (long long)K * C1; i += GT) {
            int k = (int)(i / C1), n = (int)(i - (long long)k * C1);
            a.W1t[(size_t)n * K + k] = __float2bfloat16(ld_f(a.W1, i, f32));
        }
        for (long long i = gt; i < (long long)C1 * C2; i += GT) {
            int k = (int)(i / C2), n = (int)(i - (long long)k * C2);
            a.W2t[(size_t)n * C1 + k] = __float2bfloat16(ld_f(a.W2, i, f32));
        }
        if (f32) {
            long long n8 = (long long)Mpad * K / 8;
            long long nv = (long long)N * K;
            for (long long i = gt; i < n8; i += GT) {
                long long base = i * 8;
                uint4 out;
                if (base + 8 <= nv) {
                    const float4* s4 = (const float4*)a.x_raw;
                    float4 x0 = s4[i * 2], x1 = s4[i * 2 + 1];
                    out.x = pack_bf2(x0.x, x0.y);
                    out.y = pack_bf2(x0.z, x0.w);
                    out.z = pack_bf2(x1.x, x1.y);
                    out.w = pack_bf2(x1.z, x1.w);
                } else {
                    bf16 tmp[8];
#pragma unroll
                    for (int j = 0; j < 8; j++) {
                        long long kk = base + j;
                        tmp[j] = (kk < nv) ? __float2bfloat16(ld_f(a.x_raw, kk, true))
                                           : __float2bfloat16(0.f);
                    }
                    out = *(uint4*)tmp;
                }
                ((uint4*)a.xb)[i] = out;
            }
        }
        int R0 = nfull * 128;
        for (long long i = gt; i < (long long)128 * K; i += GT) {
            int r = (int)(i / K);
            long long src = (long long)(R0 + r) * K + (i - (long long)r * K);
            a.xtail[i] = (R0 + r < N) ? __float2bfloat16(ld_f(a.x_raw, src, f32))
                                      : __float2bfloat16(0.f);
        }
    }
    grid.sync();

    // ---- P3: scan step a — per-block partial sums of deg ----
    const int CH = (N + G - 1) / G;
    const int cb = blk * CH;
    const int ce = min(N, cb + CH);
    {
        int* ss = (int*)smem;
        int local = 0;
        for (int i = cb + tid; i < ce; i += 256) local += deg[i];
        ss[tid] = local;
        __syncthreads();
        for (int s = 128; s > 0; s >>= 1) {
            if (tid < s) ss[tid] += ss[tid + s];
            __syncthreads();
        }
        if (tid == 0) a.bsum[blk] = ss[0];
    }
    grid.sync();

    // ---- P4: scan step b — block 0 exclusive-scans the G partials ----
    if (blk == 0) {
        int* ss = (int*)smem;
        int per = (G + 255) / 256;
        int b0 = tid * per, b1 = min(G, b0 + per);
        int s = 0;
        for (int i = b0; i < b1; i++) s += a.bsum[i];
        ss[tid] = s;
        __syncthreads();
        for (int off = 1; off < 256; off <<= 1) {
            int x = (tid >= off) ? ss[tid - off] : 0;
            __syncthreads();
            ss[tid] += x;
            __syncthreads();
        }
        int run = ss[tid] - s;
        for (int i = b0; i < b1; i++) {
            int v = a.bsum[i];
            a.bsum[i] = run;
            run += v;
        }
        if (tid == 255) a.rowptr[N] = ss[255];
    }
    grid.sync();

    // ---- P5: scan step c — write rowptr for this block's chunk ----
    if (tid == 0) {
        int run = a.bsum[blk];
        for (int i = cb; i < ce; i++) { a.rowptr[i] = run; run += deg[i]; }
    }
    grid.sync();

    // ---- P6: scatter, then gemm1 (+fused al1), tiles grid-strided ----
    {
        const int is64 = (*iflag == 0);
        for (long long e = gt; e < E; e += GT) {
            int s, d;
            if (e < E0) {
                s = edge_val(a.eidx, e, is64);
                d = edge_val(a.eidx, (long long)E0 + e, is64);
            } else {
                s = d = (int)(e - E0);
            }
            if ((unsigned)s >= (unsigned)N) s = 0;
            if ((unsigned)d >= (unsigned)N) d = 0;
            int pos = a.rowptr[d] + atomicAdd(&cursor[d], 1);
            if ((unsigned)pos < (unsigned)E) a.csr_src[pos] = s;
        }
        const int mt1 = Mpad / 128;
        const int nb1 = mt1 * (C1 / 128);
        for (int t = blk; t < nb1; t += G)
            dev_gemm<128, true, 4>(smem, t % mt1, t / mt1, a.x_raw, a.xb, a.xtail,
                                   fcnt, a.W1t, a.h1, a.as1, a.ad1, al1s, al1d,
                                   N, C1, K, nfull);
    }
    grid.sync();

    // ---- P7: agg1 ----
    for (int n = blk; n < N; n += G)
        dev_agg<512, 4, true, false>(smem, n, a.h1, al1s, al1d, a.rowptr,
                                     a.csr_src, a.b1, fcnt, a.hagg, N, E);
    grid.sync();

    // ---- P8: gemm2 (+fused al2) ----
    {
        const int mt1 = Mpad / 128;
        const int nb2 = mt1 * (C2 / 64);
        for (int t = blk; t < nb2; t += G)
            dev_gemm<64, false, 1>(smem, t % mt1, t / mt1, a.hagg, nullptr, nullptr,
                                   fcnt, a.W2t, h2, a.as2, a.ad2, al2s, al2d,
                                   N, C2, C1, 0);
    }
    grid.sync();

    // ---- P9: agg2 -> out ----
    for (int n = blk; n < N; n += G)
        dev_agg<128, 1, false, true>(smem, n, h2, al2s, al2d, a.rowptr,
                                     a.csr_src, a.b2, fcnt, a.out, N, E);
}

// ---------------- fallback kernels (R9 structure, shared bodies) ------------

__global__ void k_probe(const unsigned* xw, long long nw, const int* idx, int n_half,
                        int* cnt, int* iflag) {
    long long t = blockIdx.x * (long long)blockDim.x + threadIdx.x;
    long long stride = (long long)gridDim.x * blockDim.x;
    int c = 0;
    for (long long i = t; i < nw; i += stride)
        if ((xw[i] & 0x7F80u) == 0x7F80u) c++;
    if (c) atomicAdd(cnt, c);
    int any = 0;
    for (long long i = t; i < n_half; i += stride)
        if (idx[2 * i + 1] != 0) any = 1;
    if (any) atomicOr(iflag, 1);
}

__global__ void k_count(const void* idx, const int* iflag, int E0, int N, int* deg) {
    int e = blockIdx.x * blockDim.x + threadIdx.x;
    if (e >= E0 + N) return;
    int is64 = (*iflag == 0);
    int d = (e < E0) ? edge_val(idx, (long long)E0 + e, is64) : (e - E0);
    if ((unsigned)d >= (unsigned)N) d = 0;
    atomicAdd(&deg[d], 1);
}

__global__ __launch_bounds__(1024) void k_scan(const int* deg, int* rowptr, int N) {
    __shared__ int part[1024];
    int t = threadIdx.x;
    int chunk = (N + 1023) / 1024;
    int s = t * chunk, e = min(N, s + chunk);
    int sum = 0;
    for (int i = s; i < e; i++) sum += deg[i];
    part[t] = sum;
    __syncthreads();
    for (int off = 1; off < 1024; off <<= 1) {
        int v = (t >= off) ? part[t - off] : 0;
        __syncthreads();
        part[t] += v;
        __syncthreads();
    }
    int run = (t == 0) ? 0 : part[t - 1];
    for (int i = s; i < e; i++) { rowptr[i] = run; run += deg[i]; }
    if (t == 1023) rowptr[N] = part[1023];
}

__global__ void k_scatter(const void* idx, const int* iflag, int E0, int N,
                          const int* rowptr, int* cursor, int* csr_src) {
    int e = blockIdx.x * blockDim.x + threadIdx.x;
    if (e >= E0 + N) return;
    int is64 = (*iflag == 0);
    int s, d;
    if (e < E0) {
        s = edge_val(idx, e, is64);
        d = edge_val(idx, (long long)E0 + e, is64);
    } else {
        s = d = e - E0;
    }
    if ((unsigned)s >= (unsigned)N) s = 0;
    if ((unsigned)d >= (unsigned)N) d = 0;
    int pos = rowptr[d] + atomicAdd(&cursor[d], 1);
    if ((unsigned)pos < (unsigned)(E0 + N)) csr_src[pos] = s;
}

__global__ void k_prep(const void* x, const int* fcnt, bf16* xb, bf16* xtail,
                       const void* W1, bf16* W1t, const void* W2, bf16* W2t,
                       bf16* hpad, int hpad_elems, int N, int K, int C1, int C2,
                       int R0, long long n_valid, long long n_total) {
    const int b = blockIdx.x;
    const int tid = threadIdx.x;
    const bool f32 = is_f32(fcnt);
    if (b < 512) {
        if (!f32) return;
        long long n8 = n_total / 8;
        for (long long i = (long long)b * 256 + tid; i < n8; i += 512LL * 256) {
            long long base = i * 8;
            uint4 out;
            if (base + 8 <= n_valid) {
                const float4* s4 = (const float4*)x;
                float4 x0 = s4[i * 2], x1 = s4[i * 2 + 1];
                out.x = pack_bf2(x0.x, x0.y);
                out.y = pack_bf2(x0.z, x0.w);
                out.z = pack_bf2(x1.x, x1.y);
                out.w = pack_bf2(x1.z, x1.w);
            } else {
                bf16 tmp[8];
#pragma unroll
                for (int j = 0; j < 8; j++) {
                    long long k = base + j;
                    tmp[j] = (k < n_valid) ? __float2bfloat16(ld_f(x, k, true))
                                           : __float2bfloat16(0.f);
                }
                out = *(uint4*)tmp;
            }
            ((uint4*)xb)[i] = out;
        }
    } else if (b < 528) {
        int total = 128 * K;
        for (int i = (b - 512) * 256 + tid; i < total; i += 16 * 256) {
            int r = i / K;
            long long src = (long long)(R0 + r) * K + (i - r * K);
            xtail[i] = (R0 + r < N) ? __float2bfloat16(ld_f(x, src, f32))
                                    : __float2bfloat16(0.f);
        }
    } else if (b < 656) {
        int total = K * C1;
        for (int i = (b - 528) * 256 + tid; i < total; i += 128 * 256) {
            int k = i / C1, n = i - k * C1;
            W1t[(size_t)n * K + k] = __float2bfloat16(ld_f(W1, i, f32));
        }
    } else if (b < 688) {
        int total = C1 * C2;
        for (int i = (b - 656) * 256 + tid; i < total; i += 32 * 256) {
            int k = i / C2, n = i - k * C2;
            W2t[(size_t)n * C1 + k] = __float2bfloat16(ld_f(W2, i, f32));
        }
    } else {
        for (int i = (b - 688) * 256 + tid; i < hpad_elems; i += 16 * 256)
            hpad[i] = __float2bfloat16(0.f);
    }
}

template <int BN, bool SEL, int H>
__global__ __launch_bounds__(256) void k_gemm_w(const void* Araw, const bf16* Aconv,
                                                const bf16* Atail, const int* fcnt,
                                                const bf16* Bt, bf16* C,
                                                const void* a_s, const void* a_d,
                                                float* als, float* ald,
                                                int M, int Nn, int K, int nfull) {
    __shared__ __align__(16) char smem[128 * 32 * 2 + BN * 32 * 2];
    dev_gemm<BN, SEL, H>(smem, blockIdx.x, blockIdx.y, Araw, Aconv, Atail, fcnt,
                         Bt, C, a_s, a_d, als, ald, M, Nn, K, nfull);
}

template <int C, int H, bool ELU, bool DYN_OUT>
__global__ __launch_bounds__(256) void k_agg_w(const bf16* feat, const float* als,
                                               const float* ald, const int* rowptr,
                                               const int* csr_src, const void* bias,
                                               const int* fcnt, void* outp,
                                               int N, int E) {
    __shared__ __align__(16) char
        smem[4 * C * 4 + 64 * ((H == 4) ? 5 : 1) * 4 + 64 * 4 + 4 * H * 4];
    dev_agg<C, H, ELU, DYN_OUT>(smem, blockIdx.x, feat, als, ald, rowptr, csr_src,
                                bias, fcnt, outp, N, E);
}

// ---------------- launch -----------------------------------------------------

extern "C" void kernel_launch(void* const* d_in, const int* in_sizes, int n_in,
                              void* d_out, int out_size, void* d_ws, size_t ws_size,
                              hipStream_t stream) {
    const int N = in_sizes[0] / 512;  // 20000
    const int K = 512;
    const int C1 = 512;
    const int C2 = 128;
    const int E0 = in_sizes[1] / 2;   // 320000
    const int E = E0 + N;
    const int Mpad = (N + 127) / 128 * 128;  // 20096
    const int nfull = N / 128;

    char* ws = (char*)d_ws;
    size_t off = 0;
    auto take = [&](size_t bytes) {
        size_t r = off;
        off += (bytes + 255) & ~(size_t)255;
        return r;
    };
    bf16* xb     = (bf16*)(ws + take((size_t)Mpad * K * 2));
    bf16* xtail  = (bf16*)(ws + take((size_t)128 * K * 2));
    bf16* h1     = (bf16*)(ws + take((size_t)N * C1 * 2));
    bf16* hagg   = (bf16*)(ws + take((size_t)Mpad * C1 * 2));
    bf16* W1t    = (bf16*)(ws + take((size_t)K * C1 * 2));
    bf16* W2t    = (bf16*)(ws + take((size_t)C1 * C2 * 2));
    int* rowptr  = (int*)(ws + take((size_t)(N + 1) * 4));
    int* csr_src = (int*)(ws + take((size_t)E * 4));
    int* zbase   = (int*)(ws + take((size_t)(12 * N + 2) * 4));
    int* bsum    = (int*)(ws + take((size_t)4096 * 4));
    if (off > ws_size) return;  // visible failure

    MegaArgs a;
    a.x_raw = d_in[0]; a.eidx = d_in[1];
    a.W1 = d_in[2]; a.as1 = d_in[3]; a.ad1 = d_in[4]; a.b1 = d_in[5];
    a.W2 = d_in[6]; a.as2 = d_in[7]; a.ad2 = d_in[8]; a.b2 = d_in[9];
    a.xb = xb; a.xtail = xtail; a.h1 = h1; a.hagg = hagg;
    a.W1t = W1t; a.W2t = W2t;
    a.rowptr = rowptr; a.csr_src = csr_src; a.zbase = zbase; a.bsum = bsum;
    a.out = d_out;
    a.N = N; a.K = K; a.C1 = C1; a.C2 = C2;
    a.E0 = E0; a.E = E; a.Mpad = Mpad; a.nfull = nfull;
    long long nw = (long long)in_sizes[0] / 2;
    a.nw_cap = nw > (1 << 20) ? (1 << 20) : nw;
    a.nh_cap = E0 > (1 << 16) ? (1 << 16) : E0;

    // --- size the cooperative grid from the runtime's own occupancy ---
    int dev = 0;
    hipGetDevice(&dev);
    int coop = 0, numCU = 0, nbPerCU = 0;
    hipDeviceGetAttribute(&coop, hipDeviceAttributeCooperativeLaunch, dev);
    hipDeviceGetAttribute(&numCU, hipDeviceAttributeMultiprocessorCount, dev);
    hipError_t oe = hipOccupancyMaxActiveBlocksPerMultiprocessor(
        &nbPerCU, reinterpret_cast<const void*>(&k_mega), 256, 0);

    if (coop && oe == hipSuccess && nbPerCU >= 1 && numCU >= 1) {
        int G = nbPerCU * numCU;
        if (G > 4096) G = 4096;
        void* params[] = {&a};
        hipError_t e = hipLaunchCooperativeKernel(
            reinterpret_cast<const void*>(&k_mega), dim3(G), dim3(256),
            params, 0, stream);
        if (e == hipSuccess) return;
    }

    // --- fallback: proven multi-kernel sequence (R9) ---
    float* al1s = (float*)(zbase + 2 * N);
    float* al1d = al1s + 4 * N;
    float* al2s = al1d + 4 * N;
    float* al2d = al2s + N;
    int* deg = zbase;
    int* cursor = zbase + N;
    int* iflag = zbase + 12 * N;
    int* fcnt = zbase + 12 * N + 1;
    bf16* h2 = xb;

    hipMemsetAsync(zbase, 0, (size_t)(12 * N + 2) * 4, stream);
    k_probe<<<256, 256, 0, stream>>>((const unsigned*)a.x_raw, a.nw_cap,
                                     (const int*)a.eidx, a.nh_cap, fcnt, iflag);
    k_count<<<(E + 255) / 256, 256, 0, stream>>>(a.eidx, iflag, E0, N, deg);
    k_scan<<<1, 1024, 0, stream>>>(deg, rowptr, N);
    k_scatter<<<(E + 255) / 256, 256, 0, stream>>>(a.eidx, iflag, E0, N, rowptr,
                                                   cursor, csr_src);
    k_prep<<<704, 256, 0, stream>>>(a.x_raw, fcnt, xb, xtail, a.W1, W1t, a.W2, W2t,
                                    hagg + (size_t)N * C1, (Mpad - N) * C1,
                                    N, K, C1, C2, nfull * 128,
                                    (long long)N * K, (long long)Mpad * K);
    dim3 g1(Mpad / 128, C1 / 128);
    k_gemm_w<128, true, 4><<<g1, 256, 0, stream>>>(a.x_raw, xb, xtail, fcnt, W1t, h1,
                                                   a.as1, a.ad1, al1s, al1d,
                                                   N, C1, K, nfull);
    k_agg_w<512, 4, true, false><<<N, 256, 0, stream>>>(h1, al1s, al1d, rowptr,
                                                        csr_src, a.b1, fcnt, hagg,
                                                        N, E);
    dim3 g2(Mpad / 128, C2 / 64);
    k_gemm_w<64, false, 1><<<g2, 256, 0, stream>>>(hagg, nullptr, nullptr, fcnt, W2t,
                                                   h2, a.as2, a.ad2, al2s, al2d,
                                                   N, C2, C1, 0);
    k_agg_w<128, 1, false, true><<<N, 256, 0, stream>>>(h2, al2s, al2d, rowptr,
                                                        csr_src, a.b2, fcnt, d_out,
                                                        N, E);
}